// Round 13
// baseline (235.430 us; speedup 1.0000x reference)
//
#include <hip/hip_runtime.h>
#include <float.h>
#include <limits.h>

#define NB     16
#define QLEN   32
#define HDIM   128
#define NPIDS  500
#define NDOCS  10000
#define DLEN   200
#define TOPK   100
#define VROW   (DLEN * HDIM)
#define NJOBS  (NB * NPIDS)
#define NBINS  (NDOCS + 1)
#define NENT   8192          // padded entry table (>= max 8000 entries)
#define SENT   0x7FFFFFFF    // sentinel pid for unused entries

#define UNIT_BYTES 8192      // 32 tokens x 256 B
#define RING_UNITS 4
#define NUNITS     14        // 7 tiles x 2 k-halves

typedef _Float16 f16x8 __attribute__((ext_vector_type(8)));
typedef float    f32x16 __attribute__((ext_vector_type(16)));

// ---------------- Kernel 1: per-row sort + dedupe (dup -> -1) ----------------
__global__ __launch_bounds__(512) void dedupe_kernel(const int* __restrict__ pids,
                                                     const int* __restrict__ boundaries,
                                                     int* __restrict__ dpids) {
    __shared__ int s[512];
    const int b = blockIdx.x;
    const int t = threadIdx.x;
    const int lo = boundaries[0];

    int v = INT_MAX;
    if (t < NPIDS) {
        int p = pids[b * NPIDS + t] - lo;
        if (p < 0 || p >= NDOCS) p = -1;
        v = p;
    }
    s[t] = v;
    __syncthreads();

    for (int k = 2; k <= 512; k <<= 1) {
        for (int j = k >> 1; j > 0; j >>= 1) {
            int ixj = t ^ j;
            if (ixj > t) {
                int a = s[t], c = s[ixj];
                bool up = ((t & k) == 0);
                if ((a > c) == up) { s[t] = c; s[ixj] = a; }
            }
            __syncthreads();
        }
    }

    if (t < NPIDS) {
        int val = s[t];
        int o = val;
        if (val == INT_MAX) o = -1;
        else if (t > 0 && val == s[t - 1]) o = -1;
        dpids[b * NPIDS + t] = o;
    }
}

// ---------------- sort/pair pipeline ----------------
__global__ __launch_bounds__(512) void init_kernel(int* __restrict__ counts,
                                                   int* __restrict__ counter,
                                                   int2* __restrict__ entries) {
    int i = blockIdx.x * 512 + threadIdx.x;
    if (i < NBINS) counts[i] = 0;
    if (i == 0) *counter = 0;
    if (i < NENT) entries[i] = make_int2(SENT, -1);
}

__global__ __launch_bounds__(512) void hist_kernel(const int* __restrict__ dpids,
                                                   int* __restrict__ counts) {
    int i = blockIdx.x * 512 + threadIdx.x;
    if (i < NJOBS) {
        int p = dpids[i];
        int key = (p < 0) ? NDOCS : p;
        atomicAdd(&counts[key], 1);
    }
}

// single-block exclusive scan; writes mutable offsets AND a stable copy
__global__ __launch_bounds__(512) void scan_kernel(const int* __restrict__ counts,
                                                   int* __restrict__ offsets,
                                                   int* __restrict__ offsets0) {
    __shared__ int tmp[512];
    __shared__ int carry;
    const int t = threadIdx.x;
    if (t == 0) carry = 0;
    __syncthreads();

    for (int base = 0; base < NBINS; base += 512) {
        int x = (base + t < NBINS) ? counts[base + t] : 0;
        tmp[t] = x;
        __syncthreads();
        for (int off = 1; off < 512; off <<= 1) {
            int v = (t >= off) ? tmp[t - off] : 0;
            __syncthreads();
            tmp[t] += v;
            __syncthreads();
        }
        if (base + t < NBINS) {
            int e = carry + tmp[t] - x;
            offsets[base + t]  = e;
            offsets0[base + t] = e;
        }
        int btot = tmp[511];
        __syncthreads();
        if (t == 0) carry += btot;
        __syncthreads();
    }
}

__global__ __launch_bounds__(512) void scatter_kernel(const int* __restrict__ dpids,
                                                      int* __restrict__ offsets,
                                                      int* __restrict__ jobs) {
    int i = blockIdx.x * 512 + threadIdx.x;
    if (i < NJOBS) {
        int p = dpids[i];
        int key = (p < 0) ? NDOCS : p;
        int pos = atomicAdd(&offsets[key], 1);
        jobs[pos] = (key << 13) | i;        // key:14b | jobidx:13b
    }
}

// pair same-pid sorted jobs: run positions (0,1),(2,3),... -> one entry each.
// Every job lands in exactly one entry (leader covers itself + next-if-same-run).
__global__ __launch_bounds__(512) void pair_kernel(const int* __restrict__ jobs,
                                                   const int* __restrict__ offsets0,
                                                   int* __restrict__ counter,
                                                   int2* __restrict__ entries) {
    int i = blockIdx.x * 512 + threadIdx.x;
    if (i >= NJOBS) return;
    int e   = jobs[i];
    int key = e >> 13;
    int ja  = e & 8191;
    int rs  = offsets0[key];
    if (((i - rs) & 1) != 0) return;        // covered by the leader at i-1
    int jb = -1;
    if (i + 1 < NJOBS) {
        int e2 = jobs[i + 1];
        if ((e2 >> 13) == key) jb = e2 & 8191;
    }
    int pos = atomicAdd(counter, 1);
    entries[pos] = make_int2(key, (jb << 16) | ja);   // jb=-1 -> high16 = 0xFFFF
}

// 2-limb fp16 RN split (R11-verified, absmax 0.0): a = h + m + d, |d|<=2^-24|a|.
__device__ __forceinline__ void split2h(float a, _Float16& h, _Float16& m) {
    h = (_Float16)a;
    float r = a - (float)h;
    m = (_Float16)r;
}

__device__ __forceinline__ void split2h_pack8(const float4 c0, const float4 c1,
                                              f16x8& H, f16x8& M) {
    float f[8] = {c0.x, c0.y, c0.z, c0.w, c1.x, c1.y, c1.z, c1.w};
    f16x8 Ht, Mt;
    #pragma unroll
    for (int j = 0; j < 8; ++j) {
        _Float16 hh, mm;
        split2h(f[j], hh, mm);
        Ht[j] = hh; Mt[j] = mm;
    }
    H = Ht; M = Mt;
}

__device__ __forceinline__ void load_q_limbs(const float* __restrict__ qv, int b,
                                             int row, int half, f16x8* qh, f16x8* qm) {
    const float* qb = qv + ((size_t)b * QLEN + row) * HDIM + half * 8;
    #pragma unroll
    for (int ks = 0; ks < 8; ++ks) {
        const float4 a0 = *(const float4*)(qb + ks * 16);
        const float4 a1 = *(const float4*)(qb + ks * 16 + 4);
        split2h_pack8(a0, a1, qh[ks], qm[ks]);
    }
}

// ---------------- Kernel 2: MaxSim, doc-paired entries ----------------
// 1 wave per entry. Dual entry: two jobs (different batches) share ONE V
// stream — per ks: split V once, 3 MFMAs per job (independent acc chains).
// V staging/read identical to R12 (swizzled global_load_lds ring, counted
// vmcnt). Per-job numerics bit-identical to R11/R12.
__global__ __launch_bounds__(64) void score_kernel(const float* __restrict__ qv,
                                                   const float* __restrict__ vectors,
                                                   const int2* __restrict__ entries,
                                                   float* __restrict__ scores) {
    const int lane = threadIdx.x;
    const int row  = lane & 31;
    const int half = lane >> 5;

    // XCD-chunked swizzle: 8192 = 8 x 1024, bijective
    const int bid = blockIdx.x;
    const int v   = (bid & 7) * (NENT / 8) + (bid >> 3);

    const int2 ent = entries[v];
    const int pid  = ent.x;
    if (pid == SENT) return;
    const int ja = ent.y & 0xFFFF;
    const int jb = ent.y >> 16;                  // arithmetic: -1 if none
    if (pid >= NDOCS) {                          // invalid-pid run
        if (lane == 0) {
            scores[ja] = -__builtin_inff();
            if (jb >= 0) scores[jb] = -__builtin_inff();
        }
        return;
    }
    const bool dual = (jb >= 0);

    __shared__ __align__(16) unsigned char ring[RING_UNITS * UNIT_BYTES];

    // ---- Q limbs ----
    f16x8 qhA[8], qmA[8], qhB[8], qmB[8];
    load_q_limbs(qv, ja / NPIDS, row, half, qhA, qmA);
    if (dual) load_q_limbs(qv, jb / NPIDS, row, half, qhB, qmB);
    __builtin_amdgcn_sched_barrier(0);

    const char* vcand = (const char*)(vectors + (size_t)pid * VROW);

    auto stage = [&](int u) {
        const int tile = u >> 1, seg = u & 1;
        const int sbase = (u & 3) * UNIT_BYTES;
        #pragma unroll
        for (int i = 0; i < 8; ++i) {
            const int p  = i * 1024 + lane * 16;
            const int tp = p >> 8;
            int tg = tile * 32 + tp;
            if (tg > DLEN - 1) tg = DLEN - 1;
            const unsigned soff = (unsigned)tg * 512u + (unsigned)seg * 256u
                                + (unsigned)((p & 255) ^ ((tp & 7) << 4));
            __builtin_amdgcn_global_load_lds(
                (const __attribute__((address_space(1))) void*)(vcand + soff),
                (__attribute__((address_space(3))) void*)(&ring[sbase + i * 1024]),
                16, 0, 0);
        }
    };

    float rmaxA[16], rmaxB[16];
    #pragma unroll
    for (int j = 0; j < 16; ++j) { rmaxA[j] = -FLT_MAX; rmaxB[j] = -FLT_MAX; }

    f32x16 accA, accB;

    stage(0); stage(1); stage(2); stage(3);

    #pragma unroll
    for (int u = 0; u < NUNITS; ++u) {
        if (u <= 10)      asm volatile("s_waitcnt vmcnt(24)" ::: "memory");
        else if (u == 11) asm volatile("s_waitcnt vmcnt(16)" ::: "memory");
        else if (u == 12) asm volatile("s_waitcnt vmcnt(8)"  ::: "memory");
        else              asm volatile("s_waitcnt vmcnt(0)"  ::: "memory");

        if ((u & 1) == 0) {
            #pragma unroll
            for (int j = 0; j < 16; ++j) { accA[j] = 0.0f; accB[j] = 0.0f; }
        }

        const int ubase = (u & 3) * UNIT_BYTES;
        const int seg   = u & 1;
        const int swz   = (row & 7) << 4;
        #pragma unroll
        for (int k2 = 0; k2 < 4; ++k2) {
            const int ks   = seg * 4 + k2;
            const int off0 = row * 256 + k2 * 64 + half * 32;
            const float4 c0 = *(const float4*)&ring[ubase + (off0 ^ swz)];
            const float4 c1 = *(const float4*)&ring[ubase + ((off0 + 16) ^ swz)];
            f16x8 vh, vm;
            split2h_pack8(c0, c1, vh, vm);
            accA = __builtin_amdgcn_mfma_f32_32x32x16_f16(qhA[ks], vh, accA, 0, 0, 0);
            accA = __builtin_amdgcn_mfma_f32_32x32x16_f16(qhA[ks], vm, accA, 0, 0, 0);
            accA = __builtin_amdgcn_mfma_f32_32x32x16_f16(qmA[ks], vh, accA, 0, 0, 0);
            if (dual) {
                accB = __builtin_amdgcn_mfma_f32_32x32x16_f16(qhB[ks], vh, accB, 0, 0, 0);
                accB = __builtin_amdgcn_mfma_f32_32x32x16_f16(qhB[ks], vm, accB, 0, 0, 0);
                accB = __builtin_amdgcn_mfma_f32_32x32x16_f16(qmB[ks], vh, accB, 0, 0, 0);
            }
        }

        if (u & 1) {
            #pragma unroll
            for (int j = 0; j < 16; ++j) {
                rmaxA[j] = fmaxf(rmaxA[j], accA[j]);
                rmaxB[j] = fmaxf(rmaxB[j], accB[j]);
            }
        }

        __builtin_amdgcn_sched_barrier(0);
        if (u + 4 < NUNITS) stage(u + 4);
    }

    // epilogue per job
    {
        double dsum = 0.0;
        #pragma unroll
        for (int j = 0; j < 16; ++j) {
            float m = rmaxA[j];
            m = fmaxf(m, __shfl_xor(m, 1));
            m = fmaxf(m, __shfl_xor(m, 2));
            m = fmaxf(m, __shfl_xor(m, 4));
            m = fmaxf(m, __shfl_xor(m, 8));
            m = fmaxf(m, __shfl_xor(m, 16));
            dsum += (double)m;
        }
        dsum += __shfl_xor(dsum, 32);
        if (lane == 0) scores[ja] = (float)dsum;
    }
    if (dual) {
        double dsum = 0.0;
        #pragma unroll
        for (int j = 0; j < 16; ++j) {
            float m = rmaxB[j];
            m = fmaxf(m, __shfl_xor(m, 1));
            m = fmaxf(m, __shfl_xor(m, 2));
            m = fmaxf(m, __shfl_xor(m, 4));
            m = fmaxf(m, __shfl_xor(m, 8));
            m = fmaxf(m, __shfl_xor(m, 16));
            dsum += (double)m;
        }
        dsum += __shfl_xor(dsum, 32);
        if (lane == 0) scores[jb] = (float)dsum;
    }
}

// ---------------- Kernel 3: per-batch top-100 (sorted desc) ----------------
__global__ __launch_bounds__(512) void topk_kernel(const float* __restrict__ scores,
                                                   const int* __restrict__ dpids,
                                                   const int* __restrict__ boundaries,
                                                   float* __restrict__ out) {
    __shared__ float ss[512];
    __shared__ int   sp[512];
    const int b = blockIdx.x;
    const int t = threadIdx.x;
    const int lo = boundaries[0];

    float sc = -__builtin_inff();
    int   p  = -1;
    if (t < NPIDS) {
        p = dpids[b * NPIDS + t];
        sc = (p < 0) ? -__builtin_inff() : scores[b * NPIDS + t];
    }
    ss[t] = sc;
    sp[t] = p;
    __syncthreads();

    for (int k = 2; k <= 512; k <<= 1) {
        for (int j = k >> 1; j > 0; j >>= 1) {
            int ixj = t ^ j;
            if (ixj > t) {
                float a = ss[t], c = ss[ixj];
                bool down = ((t & k) == 0);
                bool swap = down ? (a < c) : (a > c);
                if (swap) {
                    int pa = sp[t], pc = sp[ixj];
                    ss[t] = c;   ss[ixj] = a;
                    sp[t] = pc;  sp[ixj] = pa;
                }
            }
            __syncthreads();
        }
    }

    if (t < TOPK) {
        out[b * TOPK + t] = ss[t];
        int pp = sp[t];
        out[NB * TOPK + b * TOPK + t] = (pp >= 0) ? (float)(pp + lo) : -1.0f;
    }
}

// ---------------- launch ----------------
extern "C" void kernel_launch(void* const* d_in, const int* in_sizes, int n_in,
                              void* d_out, int out_size, void* d_ws, size_t ws_size,
                              hipStream_t stream) {
    const float* qv        = (const float*)d_in[0];
    const int*   pids      = (const int*)d_in[1];
    const float* vectors   = (const float*)d_in[2];
    const int*   boundaries= (const int*)d_in[3];

    char* ws = (char*)d_ws;
    int*   dpids    = (int*)(ws);               // 8000 int
    float* scores   = (float*)(ws + 32768);     // 8000 float
    int*   counts   = (int*)(ws + 65536);       // 10001 int
    int*   offsets  = (int*)(ws + 114688);      // 10001 int (mutable)
    int*   offsets0 = (int*)(ws + 163840);      // 10001 int (stable)
    int*   jobs     = (int*)(ws + 212992);      // 8000 int
    int2*  entries  = (int2*)(ws + 262144);     // 8192 int2
    int*   counter  = (int*)(ws + 327680);      // 1 int

    dedupe_kernel <<<NB, 512, 0, stream>>>(pids, boundaries, dpids);
    init_kernel   <<<(NBINS + 511) / 512, 512, 0, stream>>>(counts, counter, entries);
    hist_kernel   <<<(NJOBS + 511) / 512, 512, 0, stream>>>(dpids, counts);
    scan_kernel   <<<1, 512, 0, stream>>>(counts, offsets, offsets0);
    scatter_kernel<<<(NJOBS + 511) / 512, 512, 0, stream>>>(dpids, offsets, jobs);
    pair_kernel   <<<(NJOBS + 511) / 512, 512, 0, stream>>>(jobs, offsets0, counter, entries);
    score_kernel  <<<NENT, 64, 0, stream>>>(qv, vectors, entries, scores);
    topk_kernel   <<<NB, 512, 0, stream>>>(scores, dpids, boundaries, (float*)d_out);
}